// Round 1
// baseline (1587.878 us; speedup 1.0000x reference)
//
#include <hip/hip_runtime.h>
#include <stdint.h>

typedef unsigned int u32;
typedef unsigned long long u64;

// Monotone bijection float -> u32 (order-preserving for all non-NaN floats).
// ord(-inf) = 0x007FFFFF > 0, so ord==0 is a safe "empty segment" marker.
__device__ __forceinline__ u32 f2o(float f) {
    u32 u = __float_as_uint(f);
    return (u & 0x80000000u) ? ~u : (u | 0x80000000u);
}
__device__ __forceinline__ float o2f(u32 u) {
    return __uint_as_float((u & 0x80000000u) ? (u & 0x7fffffffu) : ~u);
}

// ---------------------------------------------------------------------------
// Packed path: 64-bit atomicMax of (ord(value)<<32 | ~j).
// Tie on value-bits -> larger ~j wins -> smaller j wins (matches segment_min).
// ---------------------------------------------------------------------------
__global__ void scatter_pack_kernel(const float* __restrict__ src,
                                    const int* __restrict__ index,
                                    u64* __restrict__ pack, int N) {
    const int c = blockIdx.y;
    const int j0 = (blockIdx.x * blockDim.x + threadIdx.x) * 4;
    const float* srow = src + (size_t)c * N;
    u64* prow = pack + (size_t)c * N;
    if (j0 + 3 < N) {
        float4 v = *reinterpret_cast<const float4*>(srow + j0);
        int4  k = *reinterpret_cast<const int4*>(index + j0);
        atomicMax(&prow[k.x], ((u64)f2o(v.x) << 32) | (u32)(~(u32)(j0 + 0)));
        atomicMax(&prow[k.y], ((u64)f2o(v.y) << 32) | (u32)(~(u32)(j0 + 1)));
        atomicMax(&prow[k.z], ((u64)f2o(v.z) << 32) | (u32)(~(u32)(j0 + 2)));
        atomicMax(&prow[k.w], ((u64)f2o(v.w) << 32) | (u32)(~(u32)(j0 + 3)));
    } else {
        for (int j = j0; j < N; ++j) {
            atomicMax(&prow[index[j]], ((u64)f2o(srow[j]) << 32) | (u32)(~(u32)j));
        }
    }
}

__device__ __forceinline__ void fin1(float s, u64 p, u32 NV, float& o, float& a) {
    u32 ord = (u32)(p >> 32);
    if (ord == 0u) {            // empty segment: seg_max = -inf
        o = s;
        a = (float)NV;
    } else {
        float m = o2f(ord);
        o = fmaxf(s, m);
        a = (m >= s) ? (float)(~(u32)p) : (float)NV;
    }
}

__global__ void finalize_pack_kernel(const float* __restrict__ src,
                                     const u64* __restrict__ pack,
                                     float* __restrict__ outv,
                                     float* __restrict__ outa,
                                     size_t total, u32 NV) {
    size_t i0 = ((size_t)blockIdx.x * blockDim.x + threadIdx.x) * 4;
    const size_t stride = (size_t)gridDim.x * blockDim.x * 4;
    for (; i0 < total; i0 += stride) {
        if (i0 + 3 < total) {
            float4 s = *reinterpret_cast<const float4*>(src + i0);
            ulonglong2 p01 = *reinterpret_cast<const ulonglong2*>(pack + i0);
            ulonglong2 p23 = *reinterpret_cast<const ulonglong2*>(pack + i0 + 2);
            float4 ov, av;
            fin1(s.x, p01.x, NV, ov.x, av.x);
            fin1(s.y, p01.y, NV, ov.y, av.y);
            fin1(s.z, p23.x, NV, ov.z, av.z);
            fin1(s.w, p23.y, NV, ov.w, av.w);
            *reinterpret_cast<float4*>(outv + i0) = ov;
            *reinterpret_cast<float4*>(outa + i0) = av;
        } else {
            for (size_t i = i0; i < total; ++i) {
                float o, a;
                fin1(src[i], pack[i], NV, o, a);
                outv[i] = o;
                outa[i] = a;
            }
        }
    }
}

// ---------------------------------------------------------------------------
// Fallback path (if ws too small): 3-pass with 32-bit atomics, all in d_out.
// ---------------------------------------------------------------------------
__global__ void scatter_max32_kernel(const float* __restrict__ src,
                                     const int* __restrict__ index,
                                     u32* __restrict__ segord, int N) {
    const int c = blockIdx.y;
    const int j0 = (blockIdx.x * blockDim.x + threadIdx.x) * 4;
    const float* srow = src + (size_t)c * N;
    u32* orow = segord + (size_t)c * N;
    if (j0 + 3 < N) {
        float4 v = *reinterpret_cast<const float4*>(srow + j0);
        int4  k = *reinterpret_cast<const int4*>(index + j0);
        atomicMax(&orow[k.x], f2o(v.x));
        atomicMax(&orow[k.y], f2o(v.y));
        atomicMax(&orow[k.z], f2o(v.z));
        atomicMax(&orow[k.w], f2o(v.w));
    } else {
        for (int j = j0; j < N; ++j) atomicMax(&orow[index[j]], f2o(srow[j]));
    }
}

__global__ void scatter_arg32_kernel(const float* __restrict__ src,
                                     const int* __restrict__ index,
                                     const u32* __restrict__ segord,
                                     int* __restrict__ argpos, int N) {
    const int c = blockIdx.y;
    const int j0 = (blockIdx.x * blockDim.x + threadIdx.x) * 4;
    const float* srow = src + (size_t)c * N;
    const u32* orow = segord + (size_t)c * N;
    int* arow = argpos + (size_t)c * N;
    if (j0 + 3 < N) {
        float4 v = *reinterpret_cast<const float4*>(srow + j0);
        int4  k = *reinterpret_cast<const int4*>(index + j0);
        if (v.x == o2f(orow[k.x])) atomicMin(&arow[k.x], j0 + 0);
        if (v.y == o2f(orow[k.y])) atomicMin(&arow[k.y], j0 + 1);
        if (v.z == o2f(orow[k.z])) atomicMin(&arow[k.z], j0 + 2);
        if (v.w == o2f(orow[k.w])) atomicMin(&arow[k.w], j0 + 3);
    } else {
        for (int j = j0; j < N; ++j) {
            if (srow[j] == o2f(orow[index[j]])) atomicMin(&arow[index[j]], j);
        }
    }
}

// In-place finalize over d_out: thread i reads segord[i], argpos[i] and writes
// out[i], arg[i] at the SAME addresses (no cross-thread hazard, no restrict).
__global__ void finalize32_kernel(const float* __restrict__ src,
                                  float* out, size_t total, u32 NV) {
    u32* segord = (u32*)out;
    u32* argpos = segord + total;
    size_t i = (size_t)blockIdx.x * blockDim.x + threadIdx.x;
    const size_t stride = (size_t)gridDim.x * blockDim.x;
    for (; i < total; i += stride) {
        float s = src[i];
        u32 ord = segord[i];
        u32 ap  = argpos[i];
        float o, a;
        if (ord == 0u) { o = s; a = (float)NV; }
        else {
            float m = o2f(ord);
            o = fmaxf(s, m);
            a = (m >= s) ? (float)ap : (float)NV;
        }
        out[i] = o;
        out[total + i] = a;
    }
}

extern "C" void kernel_launch(void* const* d_in, const int* in_sizes, int n_in,
                              void* d_out, int out_size, void* d_ws, size_t ws_size,
                              hipStream_t stream) {
    const float* src = (const float*)d_in[0];
    const int* index = (const int*)d_in[1];
    const int N = in_sizes[1];
    const int C = in_sizes[0] / N;
    const size_t total = (size_t)C * N;
    float* out = (float*)d_out;

    const int TPB = 256;
    dim3 sg((N + TPB * 4 - 1) / (TPB * 4), C);

    if (ws_size >= total * sizeof(u64)) {
        u64* pack = (u64*)d_ws;
        hipMemsetAsync(pack, 0, total * sizeof(u64), stream);
        scatter_pack_kernel<<<sg, TPB, 0, stream>>>(src, index, pack, N);
        finalize_pack_kernel<<<2048, TPB, 0, stream>>>(src, pack, out, out + total,
                                                       total, (u32)N);
    } else {
        u32* segord = (u32*)d_out;
        u32* argpos = segord + total;
        hipMemsetAsync(segord, 0, total * sizeof(u32), stream);
        hipMemsetAsync(argpos, 0x7F, total * sizeof(u32), stream);
        scatter_max32_kernel<<<sg, TPB, 0, stream>>>(src, index, segord, N);
        scatter_arg32_kernel<<<sg, TPB, 0, stream>>>(src, index, segord,
                                                     (int*)argpos, N);
        finalize32_kernel<<<2048, TPB, 0, stream>>>(src, out, total, (u32)N);
    }
}

// Round 2
// 634.730 us; speedup vs baseline: 2.5017x; 2.5017x over previous
//
#include <hip/hip_runtime.h>
#include <stdint.h>

typedef unsigned int u32;
typedef unsigned long long u64;

// Monotone bijection float -> u32 (order-preserving for all non-NaN floats).
// ord==0 only for negative-NaN, so 0 is a safe "empty segment" marker.
__device__ __forceinline__ u32 f2o(float f) {
    u32 u = __float_as_uint(f);
    return (u & 0x80000000u) ? ~u : (u | 0x80000000u);
}
__device__ __forceinline__ float o2f(u32 u) {
    return __uint_as_float((u & 0x80000000u) ? (u & 0x7fffffffu) : ~u);
}

// ---------------------------------------------------------------------------
// Transposed-pack path (C == 64).
// pack_t[k*64 + c] = max over {j : index[j]==k} of (ord(src[c][j])<<32 | ~j).
// Tie on value -> larger ~j wins -> smallest j (matches reference segment_min).
// For a fixed j, all 64 channel-atomics hit ONE contiguous 512B region.
// ---------------------------------------------------------------------------
#define TJ 64

__global__ __launch_bounds__(256) void scatter_tr_kernel(
        const float* __restrict__ src, const int* __restrict__ index,
        u64* __restrict__ packt, int N, int vec_ok) {
    __shared__ float tile[64 * 65];   // [c][jj], stride 65 -> column reads conflict-free
    __shared__ int idx[TJ];
    const int j0 = blockIdx.x * TJ;
    const int t = threadIdx.x;
    const int nj = min(TJ, N - j0);

    if (t < nj) idx[t] = index[j0 + t];

    if (nj == TJ && vec_ok) {
        const int r0 = t >> 4, q = t & 15;      // 16 rows per pass, 16 float4/row
        #pragma unroll
        for (int p = 0; p < 4; ++p) {
            const int c = r0 + p * 16;
            float4 v = *reinterpret_cast<const float4*>(src + (size_t)c * N + j0 + q * 4);
            float* d = &tile[c * 65 + q * 4];
            d[0] = v.x; d[1] = v.y; d[2] = v.z; d[3] = v.w;
        }
    } else {
        for (int e = t; e < 64 * TJ; e += 256) {
            const int c = e >> 6, jj = e & 63;
            tile[c * 65 + jj] = (jj < nj) ? src[(size_t)c * N + j0 + jj] : 0.0f;
        }
    }
    __syncthreads();

    const int lane = t & 63, w = t >> 6;
    for (int jj = w; jj < nj; jj += 4) {
        const int j = j0 + jj;
        const u32 k = (u32)idx[jj];
        const float v = tile[lane * 65 + jj];
        const u64 p = ((u64)f2o(v) << 32) | (u32)(~(u32)j);
        atomicMax(&packt[(size_t)k * 64 + lane], p);   // 64 lanes -> contiguous 512B
    }
}

__global__ __launch_bounds__(256) void finalize_tr_kernel(
        const float* __restrict__ src, const u64* __restrict__ packt,
        float* __restrict__ outv, float* __restrict__ outa, int N, u32 NV) {
    __shared__ u32 lord[64 * 65];
    __shared__ u32 larg[64 * 65];
    const int k0 = blockIdx.x * 64;
    const int t = threadIdx.x;
    const int nk = min(64, N - k0);
    const int lane = t & 63, w = t >> 6;

    for (int kk = w; kk < nk; kk += 4) {
        const u64 p = packt[(size_t)(k0 + kk) * 64 + lane];  // 512B coalesced
        lord[kk * 65 + lane] = (u32)(p >> 32);
        larg[kk * 65 + lane] = ~(u32)p;
    }
    __syncthreads();

    #pragma unroll 4
    for (int cc = 0; cc < 16; ++cc) {
        const int c = w * 16 + cc;
        if (lane < nk) {
            const size_t off = (size_t)c * N + k0 + lane;
            const float s = src[off];
            const u32 ord = lord[lane * 65 + c];
            float o, a;
            if (ord == 0u) { o = s; a = (float)NV; }
            else {
                const float m = o2f(ord);
                o = fmaxf(s, m);
                a = (m >= s) ? (float)larg[lane * 65 + c] : (float)NV;
            }
            outv[off] = o;
            outa[off] = a;
        }
    }
}

// ---------------------------------------------------------------------------
// Generic fallback (C != 64): round-1 row-major packed-atomic path.
// ---------------------------------------------------------------------------
__global__ void scatter_pack_kernel(const float* __restrict__ src,
                                    const int* __restrict__ index,
                                    u64* __restrict__ pack, int N) {
    const int c = blockIdx.y;
    const int j0 = (blockIdx.x * blockDim.x + threadIdx.x) * 4;
    const float* srow = src + (size_t)c * N;
    u64* prow = pack + (size_t)c * N;
    if (j0 + 3 < N) {
        float4 v = *reinterpret_cast<const float4*>(srow + j0);
        int4 k = *reinterpret_cast<const int4*>(index + j0);
        atomicMax(&prow[k.x], ((u64)f2o(v.x) << 32) | (u32)(~(u32)(j0 + 0)));
        atomicMax(&prow[k.y], ((u64)f2o(v.y) << 32) | (u32)(~(u32)(j0 + 1)));
        atomicMax(&prow[k.z], ((u64)f2o(v.z) << 32) | (u32)(~(u32)(j0 + 2)));
        atomicMax(&prow[k.w], ((u64)f2o(v.w) << 32) | (u32)(~(u32)(j0 + 3)));
    } else {
        for (int j = j0; j < N; ++j)
            atomicMax(&prow[index[j]], ((u64)f2o(srow[j]) << 32) | (u32)(~(u32)j));
    }
}

__global__ void finalize_pack_kernel(const float* __restrict__ src,
                                     const u64* __restrict__ pack,
                                     float* __restrict__ outv,
                                     float* __restrict__ outa,
                                     size_t total, u32 NV) {
    size_t i = (size_t)blockIdx.x * blockDim.x + threadIdx.x;
    const size_t stride = (size_t)gridDim.x * blockDim.x;
    for (; i < total; i += stride) {
        const float s = src[i];
        const u64 p = pack[i];
        const u32 ord = (u32)(p >> 32);
        float o, a;
        if (ord == 0u) { o = s; a = (float)NV; }
        else {
            const float m = o2f(ord);
            o = fmaxf(s, m);
            a = (m >= s) ? (float)(~(u32)p) : (float)NV;
        }
        outv[i] = o;
        outa[i] = a;
    }
}

extern "C" void kernel_launch(void* const* d_in, const int* in_sizes, int n_in,
                              void* d_out, int out_size, void* d_ws, size_t ws_size,
                              hipStream_t stream) {
    const float* src = (const float*)d_in[0];
    const int* index = (const int*)d_in[1];
    const int N = in_sizes[1];
    const int C = in_sizes[0] / N;
    const size_t total = (size_t)C * N;
    float* out = (float*)d_out;

    u64* pack = (u64*)d_ws;
    hipMemsetAsync(pack, 0, total * sizeof(u64), stream);

    if (C == 64 && ws_size >= total * sizeof(u64)) {
        const int nblk = (N + TJ - 1) / TJ;
        const int vec_ok = ((N & 3) == 0);
        scatter_tr_kernel<<<nblk, 256, 0, stream>>>(src, index, pack, N, vec_ok);
        finalize_tr_kernel<<<nblk, 256, 0, stream>>>(src, pack, out, out + total,
                                                     N, (u32)N);
    } else {
        const int TPB = 256;
        dim3 sg((N + TPB * 4 - 1) / (TPB * 4), C);
        scatter_pack_kernel<<<sg, TPB, 0, stream>>>(src, index, pack, N);
        finalize_pack_kernel<<<2048, TPB, 0, stream>>>(src, pack, out, out + total,
                                                       total, (u32)N);
    }
}

// Round 3
// 567.627 us; speedup vs baseline: 2.7974x; 1.1182x over previous
//
#include <hip/hip_runtime.h>
#include <stdint.h>

typedef unsigned int u32;
typedef unsigned long long u64;

// Monotone bijection float -> u32 (order-preserving for all non-NaN floats).
// ord==0 only for negative-NaN, so 0 is a safe "empty segment" marker.
__device__ __forceinline__ u32 f2o(float f) {
    u32 u = __float_as_uint(f);
    return (u & 0x80000000u) ? ~u : (u | 0x80000000u);
}
__device__ __forceinline__ float o2f(u32 u) {
    return __uint_as_float((u & 0x80000000u) ? (u & 0x7fffffffu) : ~u);
}

// ---------------------------------------------------------------------------
// Transposed-pack path (C == 64).
// pack_t[k*64 + c] = max over {j : index[j]==k} of (ord(src[c][j])<<32 | ~j).
// Tie on value -> larger ~j wins -> smallest j (matches reference segment_min).
// For a fixed j, all 64 channel-atomics hit ONE contiguous 512B region.
// ---------------------------------------------------------------------------
#define TJ 64

__global__ __launch_bounds__(256) void scatter_tr_kernel(
        const float* __restrict__ src, const int* __restrict__ index,
        u64* __restrict__ packt, int N, int vec_ok) {
    __shared__ float tile[64 * 65];   // [c][jj], stride 65 -> column reads 2-way (free)
    __shared__ int idx[TJ];
    const int j0 = blockIdx.x * TJ;
    const int t = threadIdx.x;
    const int nj = min(TJ, N - j0);

    if (t < nj) idx[t] = index[j0 + t];

    if (nj == TJ && vec_ok) {
        const int r0 = t >> 4, q = t & 15;      // 16 rows per pass, 16 float4/row
        #pragma unroll
        for (int p = 0; p < 4; ++p) {
            const int c = r0 + p * 16;
            float4 v = *reinterpret_cast<const float4*>(src + (size_t)c * N + j0 + q * 4);
            float* d = &tile[c * 65 + q * 4];
            d[0] = v.x; d[1] = v.y; d[2] = v.z; d[3] = v.w;
        }
    } else {
        for (int e = t; e < 64 * TJ; e += 256) {
            const int c = e >> 6, jj = e & 63;
            tile[c * 65 + jj] = (jj < nj) ? src[(size_t)c * N + j0 + jj] : 0.0f;
        }
    }
    __syncthreads();

    const int lane = t & 63, w = t >> 6;
    #pragma unroll 4
    for (int jj = w; jj < nj; jj += 4) {
        const int j = j0 + jj;
        const u32 k = (u32)idx[jj];
        const float v = tile[lane * 65 + jj];
        const u64 p = ((u64)f2o(v) << 32) | (u32)(~(u32)j);
        atomicMax(&packt[(size_t)k * 64 + lane], p);   // 64 lanes -> contiguous 512B
    }
}

// Fully-vectorized finalize: 64k x 64c tile per block.
// Phase A: ulonglong2 loads of packt -> split lord/larg LDS (stride 65).
// Phase B: each thread owns (c, 4 consecutive k): float4 src load + 2x float4 store.
__global__ __launch_bounds__(256) void finalize_tr_kernel(
        const float* __restrict__ src, const u64* __restrict__ packt,
        float* __restrict__ outv, float* __restrict__ outa, int N, u32 NV) {
    __shared__ u32 lord[64 * 65];
    __shared__ u32 larg[64 * 65];
    const int k0 = blockIdx.x * 64;
    const int t = threadIdx.x;
    const int nk = min(64, N - k0);

    // Phase A: nk*64 u64, as nk*32 ulonglong2 pairs.
    {
        const u64* base = packt + (size_t)k0 * 64;
        const int npairs = nk * 32;
        #pragma unroll
        for (int v = 0; v < 8; ++v) {
            const int i2 = t + v * 256;
            if (i2 < npairs) {
                const int e = i2 * 2;
                ulonglong2 p = *reinterpret_cast<const ulonglong2*>(base + e);
                const int kk = e >> 6, c = e & 63;
                lord[kk * 65 + c]     = (u32)(p.x >> 32);
                larg[kk * 65 + c]     = ~(u32)p.x;
                lord[kk * 65 + c + 1] = (u32)(p.y >> 32);
                larg[kk * 65 + c + 1] = ~(u32)p.y;
            }
        }
    }
    __syncthreads();

    // Phase B
    const int lane = t & 63, w = t >> 6;
    const int q = lane & 15, cg = lane >> 4;
    const int kq = q * 4;                 // this thread's k-quad (relative)
    #pragma unroll
    for (int p = 0; p < 4; ++p) {
        const int c = p * 16 + w * 4 + cg;
        const size_t off = (size_t)c * N + k0 + kq;
        if (kq + 3 < nk) {
            float4 s = *reinterpret_cast<const float4*>(src + off);
            float sv[4] = {s.x, s.y, s.z, s.w};
            float4 ov, av;
            float* po = &ov.x; float* pa = &av.x;
            #pragma unroll
            for (int i = 0; i < 4; ++i) {
                const u32 ord = lord[(kq + i) * 65 + c];
                float o, a;
                if (ord == 0u) { o = sv[i]; a = (float)NV; }
                else {
                    const float m = o2f(ord);
                    o = fmaxf(sv[i], m);
                    a = (m >= sv[i]) ? (float)larg[(kq + i) * 65 + c] : (float)NV;
                }
                po[i] = o; pa[i] = a;
            }
            *reinterpret_cast<float4*>(outv + off) = ov;
            *reinterpret_cast<float4*>(outa + off) = av;
        } else {
            for (int i = 0; i < 4 && kq + i < nk; ++i) {
                const float s = src[off + i];
                const u32 ord = lord[(kq + i) * 65 + c];
                float o, a;
                if (ord == 0u) { o = s; a = (float)NV; }
                else {
                    const float m = o2f(ord);
                    o = fmaxf(s, m);
                    a = (m >= s) ? (float)larg[(kq + i) * 65 + c] : (float)NV;
                }
                outv[off + i] = o;
                outa[off + i] = a;
            }
        }
    }
}

// ---------------------------------------------------------------------------
// Generic fallback (C != 64): row-major packed-atomic path.
// ---------------------------------------------------------------------------
__global__ void scatter_pack_kernel(const float* __restrict__ src,
                                    const int* __restrict__ index,
                                    u64* __restrict__ pack, int N) {
    const int c = blockIdx.y;
    const int j0 = (blockIdx.x * blockDim.x + threadIdx.x) * 4;
    const float* srow = src + (size_t)c * N;
    u64* prow = pack + (size_t)c * N;
    if (j0 + 3 < N) {
        float4 v = *reinterpret_cast<const float4*>(srow + j0);
        int4 k = *reinterpret_cast<const int4*>(index + j0);
        atomicMax(&prow[k.x], ((u64)f2o(v.x) << 32) | (u32)(~(u32)(j0 + 0)));
        atomicMax(&prow[k.y], ((u64)f2o(v.y) << 32) | (u32)(~(u32)(j0 + 1)));
        atomicMax(&prow[k.z], ((u64)f2o(v.z) << 32) | (u32)(~(u32)(j0 + 2)));
        atomicMax(&prow[k.w], ((u64)f2o(v.w) << 32) | (u32)(~(u32)(j0 + 3)));
    } else {
        for (int j = j0; j < N; ++j)
            atomicMax(&prow[index[j]], ((u64)f2o(srow[j]) << 32) | (u32)(~(u32)j));
    }
}

__global__ void finalize_pack_kernel(const float* __restrict__ src,
                                     const u64* __restrict__ pack,
                                     float* __restrict__ outv,
                                     float* __restrict__ outa,
                                     size_t total, u32 NV) {
    size_t i = (size_t)blockIdx.x * blockDim.x + threadIdx.x;
    const size_t stride = (size_t)gridDim.x * blockDim.x;
    for (; i < total; i += stride) {
        const float s = src[i];
        const u64 p = pack[i];
        const u32 ord = (u32)(p >> 32);
        float o, a;
        if (ord == 0u) { o = s; a = (float)NV; }
        else {
            const float m = o2f(ord);
            o = fmaxf(s, m);
            a = (m >= s) ? (float)(~(u32)p) : (float)NV;
        }
        outv[i] = o;
        outa[i] = a;
    }
}

extern "C" void kernel_launch(void* const* d_in, const int* in_sizes, int n_in,
                              void* d_out, int out_size, void* d_ws, size_t ws_size,
                              hipStream_t stream) {
    const float* src = (const float*)d_in[0];
    const int* index = (const int*)d_in[1];
    const int N = in_sizes[1];
    const int C = in_sizes[0] / N;
    const size_t total = (size_t)C * N;
    float* out = (float*)d_out;

    u64* pack = (u64*)d_ws;
    hipMemsetAsync(pack, 0, total * sizeof(u64), stream);

    if (C == 64 && ws_size >= total * sizeof(u64)) {
        const int nblk = (N + TJ - 1) / TJ;
        const int vec_ok = ((N & 3) == 0);
        scatter_tr_kernel<<<nblk, 256, 0, stream>>>(src, index, pack, N, vec_ok);
        finalize_tr_kernel<<<nblk, 256, 0, stream>>>(src, pack, out, out + total,
                                                     N, (u32)N);
    } else {
        const int TPB = 256;
        dim3 sg((N + TPB * 4 - 1) / (TPB * 4), C);
        scatter_pack_kernel<<<sg, TPB, 0, stream>>>(src, index, pack, N);
        finalize_pack_kernel<<<2048, TPB, 0, stream>>>(src, pack, out, out + total,
                                                       total, (u32)N);
    }
}